// Round 8
// baseline (869.007 us; speedup 1.0000x reference)
//
#include <hip/hip_runtime.h>
#include <math.h>

#define EPSV 1e-5f
#define NBMAX 680   // max buckets of 256 nodes (N=169343 -> 662)

typedef __attribute__((ext_vector_type(8))) short bf16x8;
typedef __attribute__((ext_vector_type(4))) float floatx4;

__device__ __forceinline__ unsigned short f32_to_bf16(float f) {
    unsigned int u = __float_as_uint(f);
    unsigned int r = (u + 0x7fffu + ((u >> 16) & 1u)) >> 16;  // RNE
    return (unsigned short)r;
}
__device__ __forceinline__ float bf16_lo(unsigned int u) { return __uint_as_float(u << 16); }
__device__ __forceinline__ float bf16_hi(unsigned int u) { return __uint_as_float(u & 0xffff0000u); }

// ---------------- CSR build via 2-level counting sort ----------------
// Buckets = dst >> 8 (256 nodes each). All random writes confined to LDS or to
// block-private contiguous runs / L2-resident per-bucket regions.

__global__ __launch_bounds__(256) void zero_int_kernel(int* __restrict__ p, int n) {
    int i = blockIdx.x * 256 + threadIdx.x;
    if (i < n) p[i] = 0;
}

// grid = 256 blocks, each owns a contiguous edge chunk (same chunking as bin_kernel)
__global__ __launch_bounds__(256) void bucket_hist_kernel(const int* __restrict__ ei,
                                                          int* __restrict__ hist,
                                                          int* __restrict__ btot,
                                                          int E, int nb) {
    __shared__ int lh[NBMAX];
    int t = threadIdx.x;
    for (int i = t; i < nb; i += 256) lh[i] = 0;
    __syncthreads();
    int chunk = (E + 255) >> 8;
    int beg = blockIdx.x * chunk;
    int end = min(beg + chunk, E);
    for (int e = beg + t; e < end; e += 256) {
        int d = ei[E + e];
        atomicAdd(&lh[d >> 8], 1);
    }
    __syncthreads();
    for (int i = t; i < nb; i += 256) {
        int v = lh[i];
        hist[i * 256 + blockIdx.x] = v;
        if (v) atomicAdd(&btot[i], v);
    }
}

// grid = nb blocks: block b computes bbase[b] = sum btot[0..b) and turns its
// hist row (256 per-block counts) into global write offsets.
__global__ __launch_bounds__(256) void bucket_offsets_kernel(const int* __restrict__ btot,
                                                             int* __restrict__ hist,
                                                             int* __restrict__ bbase, int E) {
    __shared__ int red[256];
    __shared__ int sa[256], sb[256];
    int b = blockIdx.x, t = threadIdx.x;
    int s = 0;
    for (int i = t; i < b; i += 256) s += btot[i];
    red[t] = s;
    __syncthreads();
    for (int off = 128; off > 0; off >>= 1) {
        if (t < off) red[t] += red[t + off];
        __syncthreads();
    }
    int mybase = red[0];
    if (t == 0) {
        bbase[b] = mybase;
        if (b == gridDim.x - 1) bbase[gridDim.x] = E;
    }
    int orig = hist[b * 256 + t];
    sa[t] = orig;
    __syncthreads();
    int* sp = sa; int* dp = sb;
    for (int off = 1; off < 256; off <<= 1) {
        int x = sp[t] + (t >= off ? sp[t - off] : 0);
        dp[t] = x;
        __syncthreads();
        int* q = sp; sp = dp; dp = q;
    }
    hist[b * 256 + t] = mybase + sp[t] - orig;
}

// grid = 256 blocks, same chunks as hist. Packed payload: (dst&255)<<24 | src.
__global__ __launch_bounds__(256) void bin_kernel(const int* __restrict__ ei,
                                                  const int* __restrict__ hist,
                                                  unsigned int* __restrict__ tmp,
                                                  int E, int nb) {
    __shared__ int cur[NBMAX];
    int t = threadIdx.x;
    for (int i = t; i < nb; i += 256) cur[i] = hist[i * 256 + blockIdx.x];
    __syncthreads();
    int chunk = (E + 255) >> 8;
    int beg = blockIdx.x * chunk;
    int end = min(beg + chunk, E);
    for (int e = beg + t; e < end; e += 256) {
        int s = ei[e];
        int d = ei[E + e];
        int pos = atomicAdd(&cur[d >> 8], 1);
        tmp[pos] = ((unsigned int)(d & 255) << 24) | (unsigned int)s;
    }
}

// grid = nb blocks: sorts its bucket's edges by node, emits rowptr/csr, per-node
// norms and the per-node degree byte (for csr weight packing).
__global__ __launch_bounds__(256) void bucket_sort_kernel(const unsigned int* __restrict__ tmp,
                                                          const int* __restrict__ bbase,
                                                          int* __restrict__ rowptr,
                                                          unsigned int* __restrict__ csr,
                                                          float* __restrict__ dinv,
                                                          float* __restrict__ selfnorm,
                                                          unsigned char* __restrict__ deg8,
                                                          int n, int E) {
    __shared__ int cnt[256];
    __shared__ int sa[256], sb[256];
    int b = blockIdx.x, t = threadIdx.x;
    int node0 = b << 8;
    int nn = min(256, n - node0);
    int ebeg = bbase[b], eend = bbase[b + 1];
    cnt[t] = 0;
    __syncthreads();
    for (int e = ebeg + t; e < eend; e += 256) {
        unsigned int v = tmp[e];
        atomicAdd(&cnt[v >> 24], 1);
    }
    __syncthreads();
    sa[t] = cnt[t];
    __syncthreads();
    int* sp = sa; int* dp = sb;
    for (int off = 1; off < 256; off <<= 1) {
        int x = sp[t] + (t >= off ? sp[t - off] : 0);
        dp[t] = x;
        __syncthreads();
        int* q = sp; sp = dp; dp = q;
    }
    int excl = sp[t] - cnt[t];
    if (t < nn) {
        rowptr[node0 + t] = ebeg + excl;
        float df = (float)(cnt[t] + 1);
        dinv[node0 + t] = rsqrtf(df);
        selfnorm[node0 + t] = 1.0f / df;
        deg8[node0 + t] = (unsigned char)(cnt[t] > 255 ? 255 : cnt[t]);
    }
    if (b == gridDim.x - 1 && t == 0) rowptr[n] = E;
    dp[t] = ebeg + excl;   // reuse free buffer as cursor
    __syncthreads();
    for (int e = ebeg + t; e < eend; e += 256) {
        unsigned int v = tmp[e];
        int lpos = atomicAdd(&dp[v >> 24], 1);
        csr[lpos] = v & 0xFFFFFFu;
    }
}

// pack deg of SOURCE node into csr top byte: one random 1B gather per edge here
// (deg8 table = 169KB, cache-resident) instead of a random 4B dinv gather per
// edge in each aggregation pass.
__global__ __launch_bounds__(256) void csr_pack_kernel(unsigned int* __restrict__ csr,
                                                       const unsigned char* __restrict__ deg8,
                                                       int E) {
    int e = blockIdx.x * 256 + threadIdx.x;
    if (e < E) {
        unsigned int s = csr[e];
        csr[e] = s | ((unsigned int)deg8[s] << 24);
    }
}

// ---------------- casts ----------------

__global__ __launch_bounds__(256) void cast_bf16_kernel(const float* __restrict__ in,
                                                        unsigned short* __restrict__ out, int n4) {
    int i = blockIdx.x * 256 + threadIdx.x;
    if (i < n4) {
        float4 f = ((const float4*)in)[i];
        ushort4 o;
        o.x = f32_to_bf16(f.x); o.y = f32_to_bf16(f.y);
        o.z = f32_to_bf16(f.z); o.w = f32_to_bf16(f.w);
        ((ushort4*)out)[i] = o;
    }
}

// W[K x M] fp32 -> Wt[M x K] bf16. Indexed by OUTPUT element: writes coalesce
// (2B x consecutive lanes), strided reads absorbed by L2 (weights are small).
__global__ __launch_bounds__(256) void cast_transpose_kernel(const float* __restrict__ in,
                                                             unsigned short* __restrict__ out,
                                                             int K, int M) {
    int i = blockIdx.x * 256 + threadIdx.x;
    if (i < K * M) {
        int m2 = i / K, k = i - m2 * K;
        out[i] = f32_to_bf16(in[(size_t)k * M + m2]);
    }
}

// ---------------- edge gather helper ----------------

__device__ __forceinline__ void acc8(float* acc, uint4 u, float wt) {
    acc[0] += wt * bf16_lo(u.x); acc[1] += wt * bf16_hi(u.x);
    acc[2] += wt * bf16_lo(u.y); acc[3] += wt * bf16_hi(u.y);
    acc[4] += wt * bf16_lo(u.z); acc[5] += wt * bf16_hi(u.z);
    acc[6] += wt * bf16_lo(u.w); acc[7] += wt * bf16_hi(u.w);
}

// ---------------- FUSED aggregate + bf16 MFMA GEMM + bias/BN/ReLU (+ layer-3 GEMM) ----
// As: unpadded stride-KT with 16B-granule XOR swizzle (granule ^= row&7):
// bank-optimal for gather writes and b128 fragment reads (8 lanes per 4-bank
// group = wave floor) with zero padding -> 32KB at KT=256.
// BsYs: Bs (per-k-step B tile) and Ys (post-epilogue y2 bounce for FUSE3) are
// time-shared in ONE buffer: Bs dead after the k-loop's final barrier; Ys dead
// before the next jt's Bs write (a barrier after the FUSE3 MFMAs closes the
// race). Ys uses stride 64 + the same granule swizzle -> 8KB.
// Total LDS at KT=256: 32768 + 8192 = 40960 exactly -> 4 blocks/CU (R5's 47.6KB
// gave only 3 -> occupancy loss was the fused2 regression).
// out_emb (Cf) is written nontemporal: it is write-once dead data whose 173MB
// of LLC allocation was evicting y1 (87MB, reused deg~14x) -> FETCH 625MB.

template <int KT, bool FUSE3>
__global__ __launch_bounds__(256, 4) void fused_agg_gemm_kernel(
    const unsigned short* __restrict__ h, const int* __restrict__ rowptr,
    const unsigned int* __restrict__ csr, const float* __restrict__ dinv,
    const float* __restrict__ selfnorm, const unsigned short* __restrict__ Wt,
    unsigned short* __restrict__ Cb, int cstride, float* __restrict__ Cf,
    const float* __restrict__ bias, const float* __restrict__ g,
    const float* __restrict__ beta, const float* __restrict__ m,
    const float* __restrict__ v, const unsigned short* __restrict__ W3t,
    unsigned short* __restrict__ H3, int nrows, int M) {
    __shared__ short As[64 * KT];                       // swizzled, no pad
    __shared__ short BsYs[FUSE3 ? 64 * 64 : 64 * 40];   // Bs / Ys time-shared
    short* Bs = BsYs;
    int tid = threadIdx.x;
    int row0 = blockIdx.x * 64;

    // ---- phase 1: aggregate 64 rows into As (swizzled granules) ----
    {
        const int L = KT / 8;        // lanes per node (16 or 32)
        const int G = 256 / L;       // nodes per pass (16 or 8)
        int sub = tid % L, grp = tid / L;
        int fb = sub * 8;
        const unsigned short* hb = h + fb;
        for (int p = 0; p < 64; p += G) {
            int r = p + grp;
            int node = row0 + r;
            uint4 ov = make_uint4(0, 0, 0, 0);
            if (node < nrows) {
                int beg = rowptr[node], end = rowptr[node + 1];
                float acc[8] = {0.f, 0.f, 0.f, 0.f, 0.f, 0.f, 0.f, 0.f};
                int e = beg;
                for (; e + 8 <= end; e += 8) {
                    unsigned int c[8];
#pragma unroll
                    for (int q = 0; q < 8; ++q) c[q] = csr[e + q];
                    uint4 u[8];
#pragma unroll
                    for (int q = 0; q < 8; ++q)
                        u[q] = *(const uint4*)(hb + (size_t)(c[q] & 0xFFFFFFu) * KT);
#pragma unroll
                    for (int q = 0; q < 8; ++q)
                        acc8(acc, u[q], rsqrtf((float)((c[q] >> 24) + 1)));
                }
                for (; e + 4 <= end; e += 4) {
                    unsigned int c0 = csr[e], c1 = csr[e + 1], c2 = csr[e + 2], c3 = csr[e + 3];
                    uint4 u0 = *(const uint4*)(hb + (size_t)(c0 & 0xFFFFFFu) * KT);
                    uint4 u1 = *(const uint4*)(hb + (size_t)(c1 & 0xFFFFFFu) * KT);
                    uint4 u2 = *(const uint4*)(hb + (size_t)(c2 & 0xFFFFFFu) * KT);
                    uint4 u3 = *(const uint4*)(hb + (size_t)(c3 & 0xFFFFFFu) * KT);
                    acc8(acc, u0, rsqrtf((float)((c0 >> 24) + 1)));
                    acc8(acc, u1, rsqrtf((float)((c1 >> 24) + 1)));
                    acc8(acc, u2, rsqrtf((float)((c2 >> 24) + 1)));
                    acc8(acc, u3, rsqrtf((float)((c3 >> 24) + 1)));
                }
                for (; e < end; ++e) {
                    unsigned int c = csr[e];
                    uint4 u = *(const uint4*)(hb + (size_t)(c & 0xFFFFFFu) * KT);
                    acc8(acc, u, rsqrtf((float)((c >> 24) + 1)));
                }
                float di = dinv[node], sn = selfnorm[node];
                uint4 us = *(const uint4*)(hb + (size_t)node * KT);
                float hs[8];
                hs[0] = bf16_lo(us.x); hs[1] = bf16_hi(us.x);
                hs[2] = bf16_lo(us.y); hs[3] = bf16_hi(us.y);
                hs[4] = bf16_lo(us.z); hs[5] = bf16_hi(us.z);
                hs[6] = bf16_lo(us.w); hs[7] = bf16_hi(us.w);
                float o[8];
#pragma unroll
                for (int j = 0; j < 8; ++j) o[j] = acc[j] * di + hs[j] * sn;
                ov.x = ((unsigned int)f32_to_bf16(o[1]) << 16) | f32_to_bf16(o[0]);
                ov.y = ((unsigned int)f32_to_bf16(o[3]) << 16) | f32_to_bf16(o[2]);
                ov.z = ((unsigned int)f32_to_bf16(o[5]) << 16) | f32_to_bf16(o[4]);
                ov.w = ((unsigned int)f32_to_bf16(o[7]) << 16) | f32_to_bf16(o[6]);
            }
            *(uint4*)(As + (size_t)r * KT + ((sub ^ (r & 7)) << 3)) = ov;
        }
    }
    // first __syncthreads inside the k-loop publishes As.

    // ---- phase 2: GEMM against staged As ----
    int wave = tid >> 6, lane = tid & 63;
    int quad = lane >> 4, l16 = lane & 15;
    int wr = (wave >> 1) * 32, wc = (wave & 1) * 32;
    int srow = tid >> 2, sseg = tid & 3;

    floatx4 acc3[3];   // FUSE3: h3 rows wave*16..+16, cols 48 (mask 40)
    if constexpr (FUSE3) {
#pragma unroll
        for (int jj = 0; jj < 3; ++jj)
#pragma unroll
            for (int r = 0; r < 4; ++r) acc3[jj][r] = 0.f;
    }

    int MT = (M + 63) >> 6;
    for (int jt = 0; jt < MT; ++jt) {
        int col0 = jt * 64;
        floatx4 acc[2][2];
#pragma unroll
        for (int i = 0; i < 2; ++i)
#pragma unroll
            for (int j = 0; j < 2; ++j)
#pragma unroll
                for (int r = 0; r < 4; ++r) acc[i][j][r] = 0.f;

        int gc = col0 + srow;
        uint4 bv = make_uint4(0, 0, 0, 0);
        if (gc < M) bv = *(const uint4*)(Wt + (size_t)gc * KT + sseg * 8);

        for (int k0 = 0; k0 < KT; k0 += 32) {
            *(uint4*)(Bs + srow * 40 + sseg * 8) = bv;
            __syncthreads();

            if (k0 + 32 < KT) {
                bv = make_uint4(0, 0, 0, 0);
                if (gc < M) bv = *(const uint4*)(Wt + (size_t)gc * KT + k0 + 32 + sseg * 8);
            }

            bf16x8 af[2], bfr[2];
#pragma unroll
            for (int i = 0; i < 2; ++i) {
                int Ra = wr + i * 16 + l16;
                af[i] = *(const bf16x8*)(As + (size_t)Ra * KT +
                                         ((((k0 >> 3) + quad) ^ (Ra & 7)) << 3));
            }
#pragma unroll
            for (int j = 0; j < 2; ++j)
                bfr[j] = *(const bf16x8*)(Bs + (wc + j * 16 + l16) * 40 + quad * 8);

#pragma unroll
            for (int i = 0; i < 2; ++i)
#pragma unroll
                for (int j = 0; j < 2; ++j)
                    acc[i][j] = __builtin_amdgcn_mfma_f32_16x16x32_bf16(af[i], bfr[j], acc[i][j], 0, 0, 0);
            __syncthreads();
        }

        float sc[2], sh[2];
#pragma unroll
        for (int j = 0; j < 2; ++j) {
            int col = col0 + wc + j * 16 + l16;
            if (bias && col < M) {
                float s = g[col] * rsqrtf(v[col] + EPSV);
                sc[j] = s;
                sh[j] = (bias[col] - m[col]) * s + beta[col];
            } else {
                sc[j] = 1.f; sh[j] = 0.f;
            }
        }

#pragma unroll
        for (int i = 0; i < 2; ++i) {
#pragma unroll
            for (int r = 0; r < 4; ++r) {
                int row = row0 + wr + i * 16 + quad * 4 + r;
                if (row >= nrows) continue;
#pragma unroll
                for (int j = 0; j < 2; ++j) {
                    int col = col0 + wc + j * 16 + l16;
                    if (col < M) {
                        float val = acc[i][j][r];
                        if (bias) val = fmaxf(val * sc[j] + sh[j], 0.f);
                        unsigned short hv = f32_to_bf16(val);
                        if constexpr (FUSE3) {
                            int yr = wr + i * 16 + quad * 4 + r;
                            int yc = wc + j * 16 + l16;
                            BsYs[yr * 64 + ((((yc >> 3) ^ (yr & 7)) << 3) | (yc & 7))] = (short)hv;
                        }
                        if (Cb) Cb[(size_t)row * cstride + col] = hv;
                        if (Cf) __builtin_nontemporal_store(val, &Cf[(size_t)row * M + col]);
                    }
                }
            }
        }

        if constexpr (FUSE3) {
            __syncthreads();   // publish Ys chunk
            // h3 += y2[:, jt*64..+64] @ W3[jt*64..+64, :]
            const bf16x8 bz = {0, 0, 0, 0, 0, 0, 0, 0};
#pragma unroll
            for (int ks = 0; ks < 2; ++ks) {
                int r3 = wave * 16 + l16;
                bf16x8 af3 = *(const bf16x8*)(BsYs + r3 * 64 +
                                              (((ks * 4 + quad) ^ (r3 & 7)) << 3));
#pragma unroll
                for (int jj = 0; jj < 3; ++jj) {
                    int c3 = jj * 16 + l16;
                    bf16x8 bf3 = bz;
                    if (c3 < 40)
                        bf3 = *(const bf16x8*)(W3t + (size_t)c3 * 256 + jt * 64 + ks * 32 + quad * 8);
                    acc3[jj] = __builtin_amdgcn_mfma_f32_16x16x32_bf16(af3, bf3, acc3[jj], 0, 0, 0);
                }
            }
            __syncthreads();   // Ys reads done before next jt overwrites BsYs (Bs)
        }
    }

    if constexpr (FUSE3) {
#pragma unroll
        for (int jj = 0; jj < 3; ++jj) {
#pragma unroll
            for (int r = 0; r < 4; ++r) {
                int row = row0 + wave * 16 + quad * 4 + r;
                int col = jj * 16 + l16;
                if (row < nrows && col < 40)
                    H3[(size_t)row * 64 + col] = f32_to_bf16(acc3[jj][r]);
            }
        }
    }
}

// ---------------- layer-3: aggregate h3 (bf16, padded rows of 64) + bias + log_softmax ----

__global__ __launch_bounds__(256) void agg3_lsm_kernel(const unsigned short* __restrict__ h3,
                                                       const int* __restrict__ rowptr,
                                                       const unsigned int* __restrict__ csr,
                                                       const float* __restrict__ dinv,
                                                       const float* __restrict__ selfnorm,
                                                       const float* __restrict__ b3,
                                                       float* __restrict__ out, int n) {
    int node = (blockIdx.x * 256 + threadIdx.x) >> 6;
    int lane = threadIdx.x & 63;
    if (node >= n) return;
    int sub = lane & 15, grp = lane >> 4;
    int beg = rowptr[node], end = rowptr[node + 1];
    const unsigned short* hb = h3 + sub * 4;

    float acc[4] = {0.f, 0.f, 0.f, 0.f};
    int e = beg + grp;
    for (; e + 4 < end; e += 8) {
        unsigned int c0 = csr[e], c1 = csr[e + 4];
        float w0 = rsqrtf((float)((c0 >> 24) + 1));
        float w1 = rsqrtf((float)((c1 >> 24) + 1));
        uint2 u0 = *(const uint2*)(hb + (size_t)(c0 & 0xFFFFFFu) * 64);
        uint2 u1 = *(const uint2*)(hb + (size_t)(c1 & 0xFFFFFFu) * 64);
        acc[0] += w0 * bf16_lo(u0.x); acc[1] += w0 * bf16_hi(u0.x);
        acc[2] += w0 * bf16_lo(u0.y); acc[3] += w0 * bf16_hi(u0.y);
        acc[0] += w1 * bf16_lo(u1.x); acc[1] += w1 * bf16_hi(u1.x);
        acc[2] += w1 * bf16_lo(u1.y); acc[3] += w1 * bf16_hi(u1.y);
    }
    for (; e < end; e += 4) {
        unsigned int c = csr[e];
        float w = rsqrtf((float)((c >> 24) + 1));
        uint2 u = *(const uint2*)(hb + (size_t)(c & 0xFFFFFFu) * 64);
        acc[0] += w * bf16_lo(u.x); acc[1] += w * bf16_hi(u.x);
        acc[2] += w * bf16_lo(u.y); acc[3] += w * bf16_hi(u.y);
    }
#pragma unroll
    for (int j = 0; j < 4; ++j) {
        acc[j] += __shfl_xor(acc[j], 16, 64);
        acc[j] += __shfl_xor(acc[j], 32, 64);
    }
    float di = dinv[node], sn = selfnorm[node];
    uint2 us = *(const uint2*)(h3 + (size_t)node * 64 + sub * 4);
    float self4[4] = {bf16_lo(us.x), bf16_hi(us.x), bf16_lo(us.y), bf16_hi(us.y)};
    int f0 = sub * 4;
    float z[4];
#pragma unroll
    for (int j = 0; j < 4; ++j) {
        int f = f0 + j;
        int fc = f < 40 ? f : 0;           // clamp to keep b3 read in-bounds
        float val = acc[j] * di + self4[j] * sn + b3[fc];
        z[j] = (f < 40) ? val : -INFINITY;
    }
    float mx = fmaxf(fmaxf(z[0], z[1]), fmaxf(z[2], z[3]));
#pragma unroll
    for (int off = 1; off < 16; off <<= 1) mx = fmaxf(mx, __shfl_xor(mx, off, 64));
    float se = expf(z[0] - mx) + expf(z[1] - mx) + expf(z[2] - mx) + expf(z[3] - mx);
#pragma unroll
    for (int off = 1; off < 16; off <<= 1) se += __shfl_xor(se, off, 64);
    float lse = logf(se);
    if (grp == 0 && sub < 10) {
        floatx4 o;
        o.x = z[0] - mx - lse; o.y = z[1] - mx - lse;
        o.z = z[2] - mx - lse; o.w = z[3] - mx - lse;
        __builtin_nontemporal_store(o, (floatx4*)(out + (size_t)node * 40 + f0));
    }
}

// ---------------- launcher ----------------

extern "C" void kernel_launch(void* const* d_in, const int* in_sizes, int n_in,
                              void* d_out, int out_size, void* d_ws, size_t ws_size,
                              hipStream_t stream) {
    const float* x  = (const float*)d_in[0];
    const int* ei   = (const int*)d_in[1];   // int32
    const float* W1 = (const float*)d_in[2];
    const float* b1 = (const float*)d_in[3];
    const float* g1 = (const float*)d_in[4];
    const float* be1 = (const float*)d_in[5];
    const float* m1 = (const float*)d_in[6];
    const float* v1 = (const float*)d_in[7];
    const float* W2 = (const float*)d_in[8];
    const float* b2 = (const float*)d_in[9];
    const float* g2 = (const float*)d_in[10];
    const float* be2 = (const float*)d_in[11];
    const float* m2 = (const float*)d_in[12];
    const float* v2 = (const float*)d_in[13];
    const float* W3 = (const float*)d_in[14];
    const float* b3 = (const float*)d_in[15];

    const int N = in_sizes[0] / 128;
    const int E = in_sizes[1] / 2;
    const int nb = (N + 255) >> 8;   // node buckets of 256

    float* out_lsm = (float*)d_out;                    // [N,40]
    float* out_emb = (float*)d_out + (size_t)N * 40;   // [N,256]

    char* ws = (char*)d_ws;
    size_t off = 0;
    auto carve = [&](size_t bytes) -> void* {
        void* p = ws + off;
        off = (off + bytes + 255) & ~(size_t)255;
        return p;
    };
    int* hist     = (int*)carve((size_t)nb * 256 * 4);
    int* btot     = (int*)carve((size_t)nb * 4);
    int* bbase    = (int*)carve((size_t)(nb + 1) * 4);
    int* rowptr   = (int*)carve((size_t)(N + 1) * 4);
    unsigned int* csr = (unsigned int*)carve((size_t)E * 4);
    float* dinv     = (float*)carve((size_t)N * 4);
    float* selfnorm = (float*)carve((size_t)N * 4);
    unsigned char* deg8 = (unsigned char*)carve((size_t)N);
    unsigned short* W1t = (unsigned short*)carve((size_t)256 * 128 * 2);
    unsigned short* W2t = (unsigned short*)carve((size_t)256 * 256 * 2);
    unsigned short* W3t = (unsigned short*)carve((size_t)40 * 256 * 2);
    unsigned short* P1 = (unsigned short*)carve((size_t)N * 256 * 2);
    unsigned short* P2 = (unsigned short*)carve((size_t)N * 256 * 2);
    (void)ws_size; (void)n_in; (void)out_size;

    unsigned short* xbf = P1;   // [N,128]
    unsigned short* y1  = P2;   // [N,256] (fused1 out)
    unsigned short* h3  = P1;   // [N,64]  (xbf dead after fused1; y2 never materialized)
    unsigned int* tmp = (unsigned int*)P2;  // binned edges, consumed before y1 written

    dim3 blk(256);

    // CSR + norms: 2-level counting sort, then pack src-degree into csr top byte
    hipLaunchKernelGGL(zero_int_kernel, dim3((nb + 255) / 256), blk, 0, stream, btot, nb);
    hipLaunchKernelGGL(bucket_hist_kernel, dim3(256), blk, 0, stream, ei, hist, btot, E, nb);
    hipLaunchKernelGGL(bucket_offsets_kernel, dim3(nb), blk, 0, stream, btot, hist, bbase, E);
    hipLaunchKernelGGL(bin_kernel, dim3(256), blk, 0, stream, ei, hist, tmp, E, nb);
    hipLaunchKernelGGL(bucket_sort_kernel, dim3(nb), blk, 0, stream, tmp, bbase, rowptr, csr,
                       dinv, selfnorm, deg8, N, E);
    hipLaunchKernelGGL(csr_pack_kernel, dim3((E + 255) / 256), blk, 0, stream, csr, deg8, E);

    // casts
    int xn4 = N * 128 / 4;
    hipLaunchKernelGGL(cast_bf16_kernel, dim3((xn4 + 255) / 256), blk, 0, stream, x, xbf, xn4);
    hipLaunchKernelGGL(cast_transpose_kernel, dim3((128 * 256 + 255) / 256), blk, 0, stream,
                       W1, W1t, 128, 256);
    hipLaunchKernelGGL(cast_transpose_kernel, dim3((256 * 256 + 255) / 256), blk, 0, stream,
                       W2, W2t, 256, 256);
    hipLaunchKernelGGL(cast_transpose_kernel, dim3((256 * 40 + 255) / 256), blk, 0, stream,
                       W3, W3t, 256, 40);

    dim3 ggrid((N + 63) / 64);

    // layer 1: fused aggregate(x,128) + GEMM(K=128,M=256) + bias+BN+ReLU -> y1
    hipLaunchKernelGGL(HIP_KERNEL_NAME(fused_agg_gemm_kernel<128, false>), ggrid, blk, 0, stream,
                       xbf, rowptr, csr, dinv, selfnorm, W1t, y1, 256,
                       (float*)nullptr, b1, g1, be1, m1, v1,
                       (const unsigned short*)nullptr, (unsigned short*)nullptr, N, 256);
    // layer 2+3a: fused aggregate(y1,256) + GEMM + BN/ReLU (fp32 out_emb, nt)
    //             + in-block h3 = y2 @ W3 (y2 never hits HBM)
    hipLaunchKernelGGL(HIP_KERNEL_NAME(fused_agg_gemm_kernel<256, true>), ggrid, blk, 0, stream,
                       y1, rowptr, csr, dinv, selfnorm, W2t, (unsigned short*)nullptr, 256,
                       out_emb, b2, g2, be2, m2, v2, W3t, h3, N, 256);
    // layer 3b: aggregate h3 + b3 + log_softmax
    hipLaunchKernelGGL(agg3_lsm_kernel, dim3((N + 3) / 4), blk, 0, stream, h3, rowptr, csr,
                       dinv, selfnorm, b3, out_lsm, N);
}

// Round 9
// 843.707 us; speedup vs baseline: 1.0300x; 1.0300x over previous
//
#include <hip/hip_runtime.h>
#include <math.h>

#define EPSV 1e-5f
#define NBMAX 680   // max buckets of 256 nodes (N=169343 -> 662)

typedef __attribute__((ext_vector_type(8))) short bf16x8;
typedef __attribute__((ext_vector_type(4))) float floatx4;

__device__ __forceinline__ unsigned short f32_to_bf16(float f) {
    unsigned int u = __float_as_uint(f);
    unsigned int r = (u + 0x7fffu + ((u >> 16) & 1u)) >> 16;  // RNE
    return (unsigned short)r;
}
__device__ __forceinline__ float bf16_lo(unsigned int u) { return __uint_as_float(u << 16); }
__device__ __forceinline__ float bf16_hi(unsigned int u) { return __uint_as_float(u & 0xffff0000u); }

// ---------------- CSR build via 2-level counting sort ----------------
// Buckets = dst >> 8 (256 nodes each). All random writes confined to LDS or to
// block-private contiguous runs / L2-resident per-bucket regions.

__global__ __launch_bounds__(256) void zero_int_kernel(int* __restrict__ p, int n) {
    int i = blockIdx.x * 256 + threadIdx.x;
    if (i < n) p[i] = 0;
}

// grid = 256 blocks, each owns a contiguous edge chunk (same chunking as bin_kernel)
__global__ __launch_bounds__(256) void bucket_hist_kernel(const int* __restrict__ ei,
                                                          int* __restrict__ hist,
                                                          int* __restrict__ btot,
                                                          int E, int nb) {
    __shared__ int lh[NBMAX];
    int t = threadIdx.x;
    for (int i = t; i < nb; i += 256) lh[i] = 0;
    __syncthreads();
    int chunk = (E + 255) >> 8;
    int beg = blockIdx.x * chunk;
    int end = min(beg + chunk, E);
    for (int e = beg + t; e < end; e += 256) {
        int d = ei[E + e];
        atomicAdd(&lh[d >> 8], 1);
    }
    __syncthreads();
    for (int i = t; i < nb; i += 256) {
        int v = lh[i];
        hist[i * 256 + blockIdx.x] = v;
        if (v) atomicAdd(&btot[i], v);
    }
}

// grid = nb blocks: block b computes bbase[b] = sum btot[0..b) and turns its
// hist row (256 per-block counts) into global write offsets.
__global__ __launch_bounds__(256) void bucket_offsets_kernel(const int* __restrict__ btot,
                                                             int* __restrict__ hist,
                                                             int* __restrict__ bbase, int E) {
    __shared__ int red[256];
    __shared__ int sa[256], sb[256];
    int b = blockIdx.x, t = threadIdx.x;
    int s = 0;
    for (int i = t; i < b; i += 256) s += btot[i];
    red[t] = s;
    __syncthreads();
    for (int off = 128; off > 0; off >>= 1) {
        if (t < off) red[t] += red[t + off];
        __syncthreads();
    }
    int mybase = red[0];
    if (t == 0) {
        bbase[b] = mybase;
        if (b == gridDim.x - 1) bbase[gridDim.x] = E;
    }
    int orig = hist[b * 256 + t];
    sa[t] = orig;
    __syncthreads();
    int* sp = sa; int* dp = sb;
    for (int off = 1; off < 256; off <<= 1) {
        int x = sp[t] + (t >= off ? sp[t - off] : 0);
        dp[t] = x;
        __syncthreads();
        int* q = sp; sp = dp; dp = q;
    }
    hist[b * 256 + t] = mybase + sp[t] - orig;
}

// grid = 256 blocks, same chunks as hist. Packed payload: (dst&255)<<24 | src.
__global__ __launch_bounds__(256) void bin_kernel(const int* __restrict__ ei,
                                                  const int* __restrict__ hist,
                                                  unsigned int* __restrict__ tmp,
                                                  int E, int nb) {
    __shared__ int cur[NBMAX];
    int t = threadIdx.x;
    for (int i = t; i < nb; i += 256) cur[i] = hist[i * 256 + blockIdx.x];
    __syncthreads();
    int chunk = (E + 255) >> 8;
    int beg = blockIdx.x * chunk;
    int end = min(beg + chunk, E);
    for (int e = beg + t; e < end; e += 256) {
        int s = ei[e];
        int d = ei[E + e];
        int pos = atomicAdd(&cur[d >> 8], 1);
        tmp[pos] = ((unsigned int)(d & 255) << 24) | (unsigned int)s;
    }
}

// grid = nb blocks: sorts its bucket's edges by node, emits rowptr/csr, per-node
// norms and the per-node degree byte (for csr weight packing).
__global__ __launch_bounds__(256) void bucket_sort_kernel(const unsigned int* __restrict__ tmp,
                                                          const int* __restrict__ bbase,
                                                          int* __restrict__ rowptr,
                                                          unsigned int* __restrict__ csr,
                                                          float* __restrict__ dinv,
                                                          float* __restrict__ selfnorm,
                                                          unsigned char* __restrict__ deg8,
                                                          int n, int E) {
    __shared__ int cnt[256];
    __shared__ int sa[256], sb[256];
    int b = blockIdx.x, t = threadIdx.x;
    int node0 = b << 8;
    int nn = min(256, n - node0);
    int ebeg = bbase[b], eend = bbase[b + 1];
    cnt[t] = 0;
    __syncthreads();
    for (int e = ebeg + t; e < eend; e += 256) {
        unsigned int v = tmp[e];
        atomicAdd(&cnt[v >> 24], 1);
    }
    __syncthreads();
    sa[t] = cnt[t];
    __syncthreads();
    int* sp = sa; int* dp = sb;
    for (int off = 1; off < 256; off <<= 1) {
        int x = sp[t] + (t >= off ? sp[t - off] : 0);
        dp[t] = x;
        __syncthreads();
        int* q = sp; sp = dp; dp = q;
    }
    int excl = sp[t] - cnt[t];
    if (t < nn) {
        rowptr[node0 + t] = ebeg + excl;
        float df = (float)(cnt[t] + 1);
        dinv[node0 + t] = rsqrtf(df);
        selfnorm[node0 + t] = 1.0f / df;
        deg8[node0 + t] = (unsigned char)(cnt[t] > 255 ? 255 : cnt[t]);
    }
    if (b == gridDim.x - 1 && t == 0) rowptr[n] = E;
    dp[t] = ebeg + excl;   // reuse free buffer as cursor
    __syncthreads();
    for (int e = ebeg + t; e < eend; e += 256) {
        unsigned int v = tmp[e];
        int lpos = atomicAdd(&dp[v >> 24], 1);
        csr[lpos] = v & 0xFFFFFFu;
    }
}

// pack deg of SOURCE node into csr top byte: one random 1B gather per edge here
// (deg8 table = 169KB, cache-resident) instead of a random 4B dinv gather per
// edge in each aggregation pass.
__global__ __launch_bounds__(256) void csr_pack_kernel(unsigned int* __restrict__ csr,
                                                       const unsigned char* __restrict__ deg8,
                                                       int E) {
    int e = blockIdx.x * 256 + threadIdx.x;
    if (e < E) {
        unsigned int s = csr[e];
        csr[e] = s | ((unsigned int)deg8[s] << 24);
    }
}

// ---------------- casts ----------------

__global__ __launch_bounds__(256) void cast_bf16_kernel(const float* __restrict__ in,
                                                        unsigned short* __restrict__ out, int n4) {
    int i = blockIdx.x * 256 + threadIdx.x;
    if (i < n4) {
        float4 f = ((const float4*)in)[i];
        ushort4 o;
        o.x = f32_to_bf16(f.x); o.y = f32_to_bf16(f.y);
        o.z = f32_to_bf16(f.z); o.w = f32_to_bf16(f.w);
        ((ushort4*)out)[i] = o;
    }
}

// W[K x M] fp32 -> Wt[M x K] bf16. Indexed by OUTPUT element: writes coalesce
// (2B x consecutive lanes), strided reads absorbed by L2 (weights are small).
__global__ __launch_bounds__(256) void cast_transpose_kernel(const float* __restrict__ in,
                                                             unsigned short* __restrict__ out,
                                                             int K, int M) {
    int i = blockIdx.x * 256 + threadIdx.x;
    if (i < K * M) {
        int m2 = i / K, k = i - m2 * K;
        out[i] = f32_to_bf16(in[(size_t)k * M + m2]);
    }
}

// ---------------- edge gather helper ----------------

__device__ __forceinline__ void acc8(float* acc, uint4 u, float wt) {
    acc[0] += wt * bf16_lo(u.x); acc[1] += wt * bf16_hi(u.x);
    acc[2] += wt * bf16_lo(u.y); acc[3] += wt * bf16_hi(u.y);
    acc[4] += wt * bf16_lo(u.z); acc[5] += wt * bf16_hi(u.z);
    acc[6] += wt * bf16_lo(u.w); acc[7] += wt * bf16_hi(u.w);
}

// ---------------- FUSED aggregate + bf16 MFMA GEMM + bias/BN/ReLU (+ layer-3 GEMM) ----
// As: unpadded stride-KT with 16B-granule XOR swizzle (granule ^= row&7) -> 32KB
// at KT=256. BsYs: Bs (k-step B tile) and Ys (FUSE3 y2 bounce) time-shared ->
// 8KB. Total 40960 -> 4 blocks/CU. R8 established the gather is service-rate
// bound (invariant to occupancy 31<->41% and unroll depth), so LDS layout is
// kept for its footprint, not expected speedup.
// NOTE: nontemporal stores REVERTED (R8: nt bypassed L2 write-combining -> 64B
// half-line HBM writes, WRITE +27MB, fused2 +11us; FETCH unchanged -> the LLC
// pollution theory was wrong).

template <int KT, bool FUSE3>
__global__ __launch_bounds__(256, 4) void fused_agg_gemm_kernel(
    const unsigned short* __restrict__ h, const int* __restrict__ rowptr,
    const unsigned int* __restrict__ csr, const float* __restrict__ dinv,
    const float* __restrict__ selfnorm, const unsigned short* __restrict__ Wt,
    unsigned short* __restrict__ Cb, int cstride, float* __restrict__ Cf,
    const float* __restrict__ bias, const float* __restrict__ g,
    const float* __restrict__ beta, const float* __restrict__ m,
    const float* __restrict__ v, const unsigned short* __restrict__ W3t,
    unsigned short* __restrict__ H3, int nrows, int M) {
    __shared__ short As[64 * KT];                       // swizzled, no pad
    __shared__ short BsYs[FUSE3 ? 64 * 64 : 64 * 40];   // Bs / Ys time-shared
    short* Bs = BsYs;
    int tid = threadIdx.x;
    int row0 = blockIdx.x * 64;

    // ---- phase 1: aggregate 64 rows into As (swizzled granules) ----
    {
        const int L = KT / 8;        // lanes per node (16 or 32)
        const int G = 256 / L;       // nodes per pass (16 or 8)
        int sub = tid % L, grp = tid / L;
        int fb = sub * 8;
        const unsigned short* hb = h + fb;
        for (int p = 0; p < 64; p += G) {
            int r = p + grp;
            int node = row0 + r;
            uint4 ov = make_uint4(0, 0, 0, 0);
            if (node < nrows) {
                int beg = rowptr[node], end = rowptr[node + 1];
                float acc[8] = {0.f, 0.f, 0.f, 0.f, 0.f, 0.f, 0.f, 0.f};
                int e = beg;
                for (; e + 8 <= end; e += 8) {
                    unsigned int c[8];
#pragma unroll
                    for (int q = 0; q < 8; ++q) c[q] = csr[e + q];
                    uint4 u[8];
#pragma unroll
                    for (int q = 0; q < 8; ++q)
                        u[q] = *(const uint4*)(hb + (size_t)(c[q] & 0xFFFFFFu) * KT);
#pragma unroll
                    for (int q = 0; q < 8; ++q)
                        acc8(acc, u[q], rsqrtf((float)((c[q] >> 24) + 1)));
                }
                for (; e + 4 <= end; e += 4) {
                    unsigned int c0 = csr[e], c1 = csr[e + 1], c2 = csr[e + 2], c3 = csr[e + 3];
                    uint4 u0 = *(const uint4*)(hb + (size_t)(c0 & 0xFFFFFFu) * KT);
                    uint4 u1 = *(const uint4*)(hb + (size_t)(c1 & 0xFFFFFFu) * KT);
                    uint4 u2 = *(const uint4*)(hb + (size_t)(c2 & 0xFFFFFFu) * KT);
                    uint4 u3 = *(const uint4*)(hb + (size_t)(c3 & 0xFFFFFFu) * KT);
                    acc8(acc, u0, rsqrtf((float)((c0 >> 24) + 1)));
                    acc8(acc, u1, rsqrtf((float)((c1 >> 24) + 1)));
                    acc8(acc, u2, rsqrtf((float)((c2 >> 24) + 1)));
                    acc8(acc, u3, rsqrtf((float)((c3 >> 24) + 1)));
                }
                for (; e < end; ++e) {
                    unsigned int c = csr[e];
                    uint4 u = *(const uint4*)(hb + (size_t)(c & 0xFFFFFFu) * KT);
                    acc8(acc, u, rsqrtf((float)((c >> 24) + 1)));
                }
                float di = dinv[node], sn = selfnorm[node];
                uint4 us = *(const uint4*)(hb + (size_t)node * KT);
                float hs[8];
                hs[0] = bf16_lo(us.x); hs[1] = bf16_hi(us.x);
                hs[2] = bf16_lo(us.y); hs[3] = bf16_hi(us.y);
                hs[4] = bf16_lo(us.z); hs[5] = bf16_hi(us.z);
                hs[6] = bf16_lo(us.w); hs[7] = bf16_hi(us.w);
                float o[8];
#pragma unroll
                for (int j = 0; j < 8; ++j) o[j] = acc[j] * di + hs[j] * sn;
                ov.x = ((unsigned int)f32_to_bf16(o[1]) << 16) | f32_to_bf16(o[0]);
                ov.y = ((unsigned int)f32_to_bf16(o[3]) << 16) | f32_to_bf16(o[2]);
                ov.z = ((unsigned int)f32_to_bf16(o[5]) << 16) | f32_to_bf16(o[4]);
                ov.w = ((unsigned int)f32_to_bf16(o[7]) << 16) | f32_to_bf16(o[6]);
            }
            *(uint4*)(As + (size_t)r * KT + ((sub ^ (r & 7)) << 3)) = ov;
        }
    }
    // first __syncthreads inside the k-loop publishes As.

    // ---- phase 2: GEMM against staged As ----
    int wave = tid >> 6, lane = tid & 63;
    int quad = lane >> 4, l16 = lane & 15;
    int wr = (wave >> 1) * 32, wc = (wave & 1) * 32;
    int srow = tid >> 2, sseg = tid & 3;

    floatx4 acc3[3];   // FUSE3: h3 rows wave*16..+16, cols 48 (mask 40)
    if constexpr (FUSE3) {
#pragma unroll
        for (int jj = 0; jj < 3; ++jj)
#pragma unroll
            for (int r = 0; r < 4; ++r) acc3[jj][r] = 0.f;
    }

    int MT = (M + 63) >> 6;
    for (int jt = 0; jt < MT; ++jt) {
        int col0 = jt * 64;
        floatx4 acc[2][2];
#pragma unroll
        for (int i = 0; i < 2; ++i)
#pragma unroll
            for (int j = 0; j < 2; ++j)
#pragma unroll
                for (int r = 0; r < 4; ++r) acc[i][j][r] = 0.f;

        int gc = col0 + srow;
        uint4 bv = make_uint4(0, 0, 0, 0);
        if (gc < M) bv = *(const uint4*)(Wt + (size_t)gc * KT + sseg * 8);

        for (int k0 = 0; k0 < KT; k0 += 32) {
            *(uint4*)(Bs + srow * 40 + sseg * 8) = bv;
            __syncthreads();

            if (k0 + 32 < KT) {
                bv = make_uint4(0, 0, 0, 0);
                if (gc < M) bv = *(const uint4*)(Wt + (size_t)gc * KT + k0 + 32 + sseg * 8);
            }

            bf16x8 af[2], bfr[2];
#pragma unroll
            for (int i = 0; i < 2; ++i) {
                int Ra = wr + i * 16 + l16;
                af[i] = *(const bf16x8*)(As + (size_t)Ra * KT +
                                         ((((k0 >> 3) + quad) ^ (Ra & 7)) << 3));
            }
#pragma unroll
            for (int j = 0; j < 2; ++j)
                bfr[j] = *(const bf16x8*)(Bs + (wc + j * 16 + l16) * 40 + quad * 8);

#pragma unroll
            for (int i = 0; i < 2; ++i)
#pragma unroll
                for (int j = 0; j < 2; ++j)
                    acc[i][j] = __builtin_amdgcn_mfma_f32_16x16x32_bf16(af[i], bfr[j], acc[i][j], 0, 0, 0);
            __syncthreads();
        }

        float sc[2], sh[2];
#pragma unroll
        for (int j = 0; j < 2; ++j) {
            int col = col0 + wc + j * 16 + l16;
            if (bias && col < M) {
                float s = g[col] * rsqrtf(v[col] + EPSV);
                sc[j] = s;
                sh[j] = (bias[col] - m[col]) * s + beta[col];
            } else {
                sc[j] = 1.f; sh[j] = 0.f;
            }
        }

#pragma unroll
        for (int i = 0; i < 2; ++i) {
#pragma unroll
            for (int r = 0; r < 4; ++r) {
                int row = row0 + wr + i * 16 + quad * 4 + r;
                if (row >= nrows) continue;
#pragma unroll
                for (int j = 0; j < 2; ++j) {
                    int col = col0 + wc + j * 16 + l16;
                    if (col < M) {
                        float val = acc[i][j][r];
                        if (bias) val = fmaxf(val * sc[j] + sh[j], 0.f);
                        unsigned short hv = f32_to_bf16(val);
                        if constexpr (FUSE3) {
                            int yr = wr + i * 16 + quad * 4 + r;
                            int yc = wc + j * 16 + l16;
                            BsYs[yr * 64 + ((((yc >> 3) ^ (yr & 7)) << 3) | (yc & 7))] = (short)hv;
                        }
                        if (Cb) Cb[(size_t)row * cstride + col] = hv;
                        if (Cf) Cf[(size_t)row * M + col] = val;
                    }
                }
            }
        }

        if constexpr (FUSE3) {
            __syncthreads();   // publish Ys chunk
            // h3 += y2[:, jt*64..+64] @ W3[jt*64..+64, :]
            const bf16x8 bz = {0, 0, 0, 0, 0, 0, 0, 0};
#pragma unroll
            for (int ks = 0; ks < 2; ++ks) {
                int r3 = wave * 16 + l16;
                bf16x8 af3 = *(const bf16x8*)(BsYs + r3 * 64 +
                                              (((ks * 4 + quad) ^ (r3 & 7)) << 3));
#pragma unroll
                for (int jj = 0; jj < 3; ++jj) {
                    int c3 = jj * 16 + l16;
                    bf16x8 bf3 = bz;
                    if (c3 < 40)
                        bf3 = *(const bf16x8*)(W3t + (size_t)c3 * 256 + jt * 64 + ks * 32 + quad * 8);
                    acc3[jj] = __builtin_amdgcn_mfma_f32_16x16x32_bf16(af3, bf3, acc3[jj], 0, 0, 0);
                }
            }
            __syncthreads();   // Ys reads done before next jt overwrites BsYs (Bs)
        }
    }

    if constexpr (FUSE3) {
#pragma unroll
        for (int jj = 0; jj < 3; ++jj) {
#pragma unroll
            for (int r = 0; r < 4; ++r) {
                int row = row0 + wave * 16 + quad * 4 + r;
                int col = jj * 16 + l16;
                if (row < nrows && col < 40)
                    H3[(size_t)row * 64 + col] = f32_to_bf16(acc3[jj][r]);
            }
        }
    }
}

// ---------------- layer-3: aggregate h3 (bf16, padded rows of 64) + bias + log_softmax ----

__global__ __launch_bounds__(256) void agg3_lsm_kernel(const unsigned short* __restrict__ h3,
                                                       const int* __restrict__ rowptr,
                                                       const unsigned int* __restrict__ csr,
                                                       const float* __restrict__ dinv,
                                                       const float* __restrict__ selfnorm,
                                                       const float* __restrict__ b3,
                                                       float* __restrict__ out, int n) {
    int node = (blockIdx.x * 256 + threadIdx.x) >> 6;
    int lane = threadIdx.x & 63;
    if (node >= n) return;
    int sub = lane & 15, grp = lane >> 4;
    int beg = rowptr[node], end = rowptr[node + 1];
    const unsigned short* hb = h3 + sub * 4;

    float acc[4] = {0.f, 0.f, 0.f, 0.f};
    int e = beg + grp;
    for (; e + 4 < end; e += 8) {
        unsigned int c0 = csr[e], c1 = csr[e + 4];
        float w0 = rsqrtf((float)((c0 >> 24) + 1));
        float w1 = rsqrtf((float)((c1 >> 24) + 1));
        uint2 u0 = *(const uint2*)(hb + (size_t)(c0 & 0xFFFFFFu) * 64);
        uint2 u1 = *(const uint2*)(hb + (size_t)(c1 & 0xFFFFFFu) * 64);
        acc[0] += w0 * bf16_lo(u0.x); acc[1] += w0 * bf16_hi(u0.x);
        acc[2] += w0 * bf16_lo(u0.y); acc[3] += w0 * bf16_hi(u0.y);
        acc[0] += w1 * bf16_lo(u1.x); acc[1] += w1 * bf16_hi(u1.x);
        acc[2] += w1 * bf16_lo(u1.y); acc[3] += w1 * bf16_hi(u1.y);
    }
    for (; e < end; e += 4) {
        unsigned int c = csr[e];
        float w = rsqrtf((float)((c >> 24) + 1));
        uint2 u = *(const uint2*)(hb + (size_t)(c & 0xFFFFFFu) * 64);
        acc[0] += w * bf16_lo(u.x); acc[1] += w * bf16_hi(u.x);
        acc[2] += w * bf16_lo(u.y); acc[3] += w * bf16_hi(u.y);
    }
#pragma unroll
    for (int j = 0; j < 4; ++j) {
        acc[j] += __shfl_xor(acc[j], 16, 64);
        acc[j] += __shfl_xor(acc[j], 32, 64);
    }
    float di = dinv[node], sn = selfnorm[node];
    uint2 us = *(const uint2*)(h3 + (size_t)node * 64 + sub * 4);
    float self4[4] = {bf16_lo(us.x), bf16_hi(us.x), bf16_lo(us.y), bf16_hi(us.y)};
    int f0 = sub * 4;
    float z[4];
#pragma unroll
    for (int j = 0; j < 4; ++j) {
        int f = f0 + j;
        int fc = f < 40 ? f : 0;           // clamp to keep b3 read in-bounds
        float val = acc[j] * di + self4[j] * sn + b3[fc];
        z[j] = (f < 40) ? val : -INFINITY;
    }
    float mx = fmaxf(fmaxf(z[0], z[1]), fmaxf(z[2], z[3]));
#pragma unroll
    for (int off = 1; off < 16; off <<= 1) mx = fmaxf(mx, __shfl_xor(mx, off, 64));
    float se = expf(z[0] - mx) + expf(z[1] - mx) + expf(z[2] - mx) + expf(z[3] - mx);
#pragma unroll
    for (int off = 1; off < 16; off <<= 1) se += __shfl_xor(se, off, 64);
    float lse = logf(se);
    if (grp == 0 && sub < 10) {
        float4 o = make_float4(z[0] - mx - lse, z[1] - mx - lse, z[2] - mx - lse, z[3] - mx - lse);
        *(float4*)(out + (size_t)node * 40 + f0) = o;
    }
}

// ---------------- launcher ----------------

extern "C" void kernel_launch(void* const* d_in, const int* in_sizes, int n_in,
                              void* d_out, int out_size, void* d_ws, size_t ws_size,
                              hipStream_t stream) {
    const float* x  = (const float*)d_in[0];
    const int* ei   = (const int*)d_in[1];   // int32
    const float* W1 = (const float*)d_in[2];
    const float* b1 = (const float*)d_in[3];
    const float* g1 = (const float*)d_in[4];
    const float* be1 = (const float*)d_in[5];
    const float* m1 = (const float*)d_in[6];
    const float* v1 = (const float*)d_in[7];
    const float* W2 = (const float*)d_in[8];
    const float* b2 = (const float*)d_in[9];
    const float* g2 = (const float*)d_in[10];
    const float* be2 = (const float*)d_in[11];
    const float* m2 = (const float*)d_in[12];
    const float* v2 = (const float*)d_in[13];
    const float* W3 = (const float*)d_in[14];
    const float* b3 = (const float*)d_in[15];

    const int N = in_sizes[0] / 128;
    const int E = in_sizes[1] / 2;
    const int nb = (N + 255) >> 8;   // node buckets of 256

    float* out_lsm = (float*)d_out;                    // [N,40]
    float* out_emb = (float*)d_out + (size_t)N * 40;   // [N,256]

    char* ws = (char*)d_ws;
    size_t off = 0;
    auto carve = [&](size_t bytes) -> void* {
        void* p = ws + off;
        off = (off + bytes + 255) & ~(size_t)255;
        return p;
    };
    int* hist     = (int*)carve((size_t)nb * 256 * 4);
    int* btot     = (int*)carve((size_t)nb * 4);
    int* bbase    = (int*)carve((size_t)(nb + 1) * 4);
    int* rowptr   = (int*)carve((size_t)(N + 1) * 4);
    unsigned int* csr = (unsigned int*)carve((size_t)E * 4);
    float* dinv     = (float*)carve((size_t)N * 4);
    float* selfnorm = (float*)carve((size_t)N * 4);
    unsigned char* deg8 = (unsigned char*)carve((size_t)N);
    unsigned short* W1t = (unsigned short*)carve((size_t)256 * 128 * 2);
    unsigned short* W2t = (unsigned short*)carve((size_t)256 * 256 * 2);
    unsigned short* W3t = (unsigned short*)carve((size_t)40 * 256 * 2);
    unsigned short* P1 = (unsigned short*)carve((size_t)N * 256 * 2);
    unsigned short* P2 = (unsigned short*)carve((size_t)N * 256 * 2);
    (void)ws_size; (void)n_in; (void)out_size;

    unsigned short* xbf = P1;   // [N,128]
    unsigned short* y1  = P2;   // [N,256] (fused1 out)
    unsigned short* h3  = P1;   // [N,64]  (xbf dead after fused1; y2 never materialized)
    unsigned int* tmp = (unsigned int*)P2;  // binned edges, consumed before y1 written

    dim3 blk(256);

    // CSR + norms: 2-level counting sort, then pack src-degree into csr top byte
    hipLaunchKernelGGL(zero_int_kernel, dim3((nb + 255) / 256), blk, 0, stream, btot, nb);
    hipLaunchKernelGGL(bucket_hist_kernel, dim3(256), blk, 0, stream, ei, hist, btot, E, nb);
    hipLaunchKernelGGL(bucket_offsets_kernel, dim3(nb), blk, 0, stream, btot, hist, bbase, E);
    hipLaunchKernelGGL(bin_kernel, dim3(256), blk, 0, stream, ei, hist, tmp, E, nb);
    hipLaunchKernelGGL(bucket_sort_kernel, dim3(nb), blk, 0, stream, tmp, bbase, rowptr, csr,
                       dinv, selfnorm, deg8, N, E);
    hipLaunchKernelGGL(csr_pack_kernel, dim3((E + 255) / 256), blk, 0, stream, csr, deg8, E);

    // casts
    int xn4 = N * 128 / 4;
    hipLaunchKernelGGL(cast_bf16_kernel, dim3((xn4 + 255) / 256), blk, 0, stream, x, xbf, xn4);
    hipLaunchKernelGGL(cast_transpose_kernel, dim3((128 * 256 + 255) / 256), blk, 0, stream,
                       W1, W1t, 128, 256);
    hipLaunchKernelGGL(cast_transpose_kernel, dim3((256 * 256 + 255) / 256), blk, 0, stream,
                       W2, W2t, 256, 256);
    hipLaunchKernelGGL(cast_transpose_kernel, dim3((256 * 40 + 255) / 256), blk, 0, stream,
                       W3, W3t, 256, 40);

    dim3 ggrid((N + 63) / 64);

    // layer 1: fused aggregate(x,128) + GEMM(K=128,M=256) + bias+BN+ReLU -> y1
    hipLaunchKernelGGL(HIP_KERNEL_NAME(fused_agg_gemm_kernel<128, false>), ggrid, blk, 0, stream,
                       xbf, rowptr, csr, dinv, selfnorm, W1t, y1, 256,
                       (float*)nullptr, b1, g1, be1, m1, v1,
                       (const unsigned short*)nullptr, (unsigned short*)nullptr, N, 256);
    // layer 2+3a: fused aggregate(y1,256) + GEMM + BN/ReLU (fp32 out_emb)
    //             + in-block h3 = y2 @ W3 (y2 never hits HBM)
    hipLaunchKernelGGL(HIP_KERNEL_NAME(fused_agg_gemm_kernel<256, true>), ggrid, blk, 0, stream,
                       y1, rowptr, csr, dinv, selfnorm, W2t, (unsigned short*)nullptr, 256,
                       out_emb, b2, g2, be2, m2, v2, W3t, h3, N, 256);
    // layer 3b: aggregate h3 + b3 + log_softmax
    hipLaunchKernelGGL(agg3_lsm_kernel, dim3((N + 3) / 4), blk, 0, stream, h3, rowptr, csr,
                       dinv, selfnorm, b3, out_lsm, N);
}